// Round 9
// baseline (291.675 us; speedup 1.0000x reference)
//
#include <hip/hip_runtime.h>
#include <hip/hip_bf16.h>

// SPRGNN: 2-layer GraphConv GNN forward. CSR-gather, f16 activation storage,
// MFMA conv, f32 accumulate. N=100000, E=1200000, G=1000.
//
// R9: (a) 8-way privatized histogram (R8 k_hist: 51us, 42MB HBM writebacks
// from cross-XCD atomic line ping-pong). copy = blockIdx&7 keeps each copy's
// lines in one XCD's L2. Combine kernel -> per-copy prefixes + totals.
// (b) layer-1 table: x has <=128 distinct rows -> h1table[128][32] in LDS;
// edge payload packs (code<<17)|src so agg1 gathers from LDS not global.

#define NGRAPHS 1000
#define SCAN_CHUNK 4096
#define SRCMASK 0x1FFFF

typedef _Float16 f16x8 __attribute__((ext_vector_type(8)));
typedef float f32x4 __attribute__((ext_vector_type(4)));

// ---------------------------------------------------------------- CSR build
// pass 1: 8-way privatized histogram; atomicAdd return = rank within copy
__global__ __launch_bounds__(256) void k_hist8(const int* __restrict__ dst,
                                               int* __restrict__ hist8,
                                               int* __restrict__ rank, int n, int nE)
{
    int e = blockIdx.x * 256 + threadIdx.x;
    if (e >= nE) return;
    int copy = blockIdx.x & 7;
    rank[e] = atomicAdd(&hist8[(size_t)copy * n + dst[e]], 1);
}

// combine: per node, exclusive prefix across the 8 copies (in place) + total
__global__ __launch_bounds__(256) void k_combine(int* __restrict__ hist8,
                                                 int* __restrict__ total, int n)
{
    int i = blockIdx.x * 256 + threadIdx.x;
    if (i >= n) return;
    int s = 0;
#pragma unroll
    for (int c = 0; c < 8; ++c) {
        int v = hist8[(size_t)c * n + i];
        hist8[(size_t)c * n + i] = s;
        s += v;
    }
    total[i] = s;
}

__global__ __launch_bounds__(256) void k_scan_part(const int* __restrict__ hist,
                                                   int* __restrict__ bsum, int n)
{
    __shared__ int s[256];
    int t = threadIdx.x;
    int beg = blockIdx.x * SCAN_CHUNK + t * 16;
    int sum = 0;
#pragma unroll
    for (int q = 0; q < 16; ++q) {
        int i = beg + q;
        if (i < n) sum += hist[i];
    }
    s[t] = sum;
    __syncthreads();
    for (int off = 128; off > 0; off >>= 1) {
        if (t < off) s[t] += s[t + off];
        __syncthreads();
    }
    if (t == 0) bsum[blockIdx.x] = s[0];
}

__global__ __launch_bounds__(64) void k_scan_mid(const int* __restrict__ bsum,
                                                 int* __restrict__ boffs,
                                                 int* __restrict__ row_ptr,
                                                 int B, int n)
{
    if (threadIdx.x == 0) {
        int run = 0;
        for (int b = 0; b < B; ++b) {
            boffs[b] = run;
            run += bsum[b];
        }
        row_ptr[n] = run;
    }
}

__global__ __launch_bounds__(256) void k_scan_apply(const int* __restrict__ hist,
                                                    const int* __restrict__ boffs,
                                                    int* __restrict__ row_ptr, int n)
{
    __shared__ int s[256];
    int t = threadIdx.x;
    int beg = blockIdx.x * SCAN_CHUNK + t * 16;
    int v[16];
    int sum = 0;
#pragma unroll
    for (int q = 0; q < 16; ++q) {
        int i = beg + q;
        v[q] = (i < n) ? hist[i] : 0;
        sum += v[q];
    }
    s[t] = sum;
    __syncthreads();
    for (int off = 1; off < 256; off <<= 1) {
        int x = (t >= off) ? s[t - off] : 0;
        __syncthreads();
        s[t] += x;
        __syncthreads();
    }
    int base = boffs[blockIdx.x] + ((t == 0) ? 0 : s[t - 1]);
#pragma unroll
    for (int q = 0; q < 16; ++q) {
        int i = beg + q;
        if (i < n) {
            row_ptr[i] = base;
            base += v[q];
        }
    }
}

// pass 2: atomic-free scatter; payload packs (code<<17)|src
__global__ __launch_bounds__(256) void k_scatteridx(
    const int* __restrict__ src, const int* __restrict__ dst,
    const int* __restrict__ row_ptr, const int* __restrict__ hist8,
    const int* __restrict__ rank, const int* __restrict__ code,
    int* __restrict__ sorted, int n, int nE)
{
    int e = blockIdx.x * 256 + threadIdx.x;
    if (e >= nE) return;
    int copy = blockIdx.x & 7;
    int d = dst[e];
    int s = src[e];
    int pos = row_ptr[d] + hist8[(size_t)copy * n + d] + rank[e];
    sorted[pos] = (code[s] << 17) | s;
}

// ---------------------------------------------------------------- K1: pre-MLP
// also emits code[i] = x0*8 + x1 (the h1-table index)
__global__ __launch_bounds__(256) void k_pre(
    const int* __restrict__ x,
    const float* __restrict__ shape_emb, const float* __restrict__ color_emb,
    const float* __restrict__ W_pre, const float* __restrict__ b_pre,
    _Float16* __restrict__ h1, int* __restrict__ code, int n)
{
    __shared__ float sW[32 * 16];
    __shared__ float sB[32];
    __shared__ float sSE[16 * 8];
    __shared__ float sCE[8 * 8];
    int t = threadIdx.x;
    for (int i = t; i < 32 * 16; i += 256) sW[i] = W_pre[i];
    if (t < 32) sB[t] = b_pre[t];
    for (int i = t; i < 16 * 8; i += 256) sSE[i] = shape_emb[i];
    if (t < 64) sCE[t] = color_emb[t];
    __syncthreads();

    int i = blockIdx.x * 256 + t;
    if (i >= n) return;
    int s = x[2 * i];
    int c = x[2 * i + 1];
    code[i] = (s << 3) | (c & 7);
    float in[16];
#pragma unroll
    for (int k = 0; k < 8; ++k) in[k] = sSE[s * 8 + k];
#pragma unroll
    for (int k = 0; k < 8; ++k) in[8 + k] = sCE[c * 8 + k];

    float acc[32];
#pragma unroll
    for (int j = 0; j < 32; ++j) acc[j] = sB[j];
#pragma unroll
    for (int k = 0; k < 16; ++k) {
        float v = in[k];
#pragma unroll
        for (int j = 0; j < 32; ++j) acc[j] += sW[j * 16 + k] * v;
    }
#pragma unroll
    for (int g = 0; g < 4; ++g) {
        f16x8 o;
#pragma unroll
        for (int q = 0; q < 8; ++q) o[q] = (_Float16)fmaxf(acc[g * 8 + q], 0.f);
        *(f16x8*)(h1 + (size_t)i * 32 + g * 8) = o;
    }
}

// ------------------------------------------ h1 table: one row per input combo
__global__ __launch_bounds__(128) void k_table(
    const float* __restrict__ shape_emb, const float* __restrict__ color_emb,
    const float* __restrict__ W_pre, const float* __restrict__ b_pre,
    _Float16* __restrict__ table)   // [128][32]
{
    int c = threadIdx.x;            // code
    int si = c >> 3, ci = c & 7;
    float in[16];
#pragma unroll
    for (int k = 0; k < 8; ++k) in[k] = shape_emb[si * 8 + k];
#pragma unroll
    for (int k = 0; k < 8; ++k) in[8 + k] = color_emb[ci * 8 + k];
    float acc[32];
#pragma unroll
    for (int j = 0; j < 32; ++j) acc[j] = b_pre[j];
#pragma unroll
    for (int k = 0; k < 16; ++k) {
        float v = in[k];
#pragma unroll
        for (int j = 0; j < 32; ++j) acc[j] += W_pre[j * 16 + k] * v;
    }
#pragma unroll
    for (int g = 0; g < 4; ++g) {
        f16x8 o;
#pragma unroll
        for (int q = 0; q < 8; ++q) o[q] = (_Float16)fmaxf(acc[g * 8 + q], 0.f);
        *(f16x8*)(table + (size_t)c * 32 + g * 8) = o;
    }
}

// --------------------------------- agg1: gather from LDS h1-table (no global)
// PARTS=4 threads/node; payload rows come from the 8KB LDS table via code.
__global__ __launch_bounds__(256) void k_agg1_tab(
    const int* __restrict__ row_ptr, const int* __restrict__ sorted,
    const _Float16* __restrict__ table, _Float16* __restrict__ agg, int n)
{
    __shared__ _Float16 tab[128 * 32];
    int t = threadIdx.x;
    for (int i = t * 8; i < 128 * 32; i += 256 * 8)
        *(f16x8*)(tab + i) = *(const f16x8*)(table + i);
    __syncthreads();

    int tid = blockIdx.x * 256 + t;
    int i = tid >> 2;
    int p = tid & 3;
    if (i >= n) return;
    float a[8] = {0, 0, 0, 0, 0, 0, 0, 0};
    float b[8] = {0, 0, 0, 0, 0, 0, 0, 0};
    int e0 = row_ptr[i], e1 = row_ptr[i + 1];
    const _Float16* tp = tab + p * 8;
    int e = e0;
    for (; e + 2 <= e1; e += 2) {
        int c0 = sorted[e] >> 17;
        int c1 = sorted[e + 1] >> 17;
        f16x8 r0 = *(const f16x8*)(tp + c0 * 32);
        f16x8 r1 = *(const f16x8*)(tp + c1 * 32);
#pragma unroll
        for (int q = 0; q < 8; ++q) { a[q] += (float)r0[q]; b[q] += (float)r1[q]; }
    }
    if (e < e1) {
        int c0 = sorted[e] >> 17;
        f16x8 r0 = *(const f16x8*)(tp + c0 * 32);
#pragma unroll
        for (int q = 0; q < 8; ++q) a[q] += (float)r0[q];
    }
    f16x8 o;
#pragma unroll
    for (int q = 0; q < 8; ++q) o[q] = (_Float16)(a[q] + b[q]);
    *(f16x8*)(agg + (size_t)i * 32 + p * 8) = o;
}

// ------------------------------------------------- agg2: gather via CSR (global)
// PARTS threads/node; each owns 8 f16 channels. Edge loop unrolled x4.
template <int WIDTH, int PARTS>
__global__ __launch_bounds__(256) void k_agg(
    const int* __restrict__ row_ptr, const int* __restrict__ sorted,
    const _Float16* __restrict__ h, _Float16* __restrict__ agg, int n)
{
    int tid = blockIdx.x * 256 + threadIdx.x;
    int i = tid / PARTS;
    int p = tid % PARTS;
    if (i >= n) return;
    float a[8] = {0, 0, 0, 0, 0, 0, 0, 0};
    float b[8] = {0, 0, 0, 0, 0, 0, 0, 0};
    int e0 = row_ptr[i], e1 = row_ptr[i + 1];
    const _Float16* hp = h + p * 8;
    int e = e0;
    for (; e + 4 <= e1; e += 4) {
        int s0 = sorted[e] & SRCMASK;
        int s1 = sorted[e + 1] & SRCMASK;
        int s2 = sorted[e + 2] & SRCMASK;
        int s3 = sorted[e + 3] & SRCMASK;
        f16x8 r0 = *(const f16x8*)(hp + (size_t)s0 * WIDTH);
        f16x8 r1 = *(const f16x8*)(hp + (size_t)s1 * WIDTH);
        f16x8 r2 = *(const f16x8*)(hp + (size_t)s2 * WIDTH);
        f16x8 r3 = *(const f16x8*)(hp + (size_t)s3 * WIDTH);
#pragma unroll
        for (int q = 0; q < 8; ++q) {
            a[q] += (float)r0[q] + (float)r2[q];
            b[q] += (float)r1[q] + (float)r3[q];
        }
    }
    for (; e < e1; ++e) {
        int s0 = sorted[e] & SRCMASK;
        f16x8 r0 = *(const f16x8*)(hp + (size_t)s0 * WIDTH);
#pragma unroll
        for (int q = 0; q < 8; ++q) a[q] += (float)r0[q];
    }
    f16x8 o;
#pragma unroll
    for (int q = 0; q < 8; ++q) o[q] = (_Float16)(a[q] + b[q]);
    *(f16x8*)(agg + (size_t)i * WIDTH + p * 8) = o;
}

// ---------------------------------------------------- conv via MFMA
template <int WIN>
__global__ __launch_bounds__(256) void k_conv_mfma(
    const _Float16* __restrict__ agg, const _Float16* __restrict__ h,
    const float* __restrict__ W_rel, const float* __restrict__ b_rel,
    const float* __restrict__ W_root, _Float16* __restrict__ out, int n)
{
    constexpr int NK = (2 * WIN) / 32;
    int t = threadIdx.x;
    int lane = t & 63;
    int w = t >> 6;
    int col = lane & 15;
    int krow = lane >> 4;

    f16x8 B[NK][4];
#pragma unroll
    for (int ks = 0; ks < NK; ++ks) {
#pragma unroll
        for (int ct = 0; ct < 4; ++ct) {
            int j = ct * 16 + col;
            int kb = ks * 32 + krow * 8;
            const float* srcw = (ks < NK / 2)
                ? (W_rel + (size_t)j * WIN + kb)
                : (W_root + (size_t)j * WIN + (kb - WIN));
            float4 w0 = *(const float4*)(srcw);
            float4 w1 = *(const float4*)(srcw + 4);
            f16x8 bb;
            bb[0] = (_Float16)w0.x; bb[1] = (_Float16)w0.y;
            bb[2] = (_Float16)w0.z; bb[3] = (_Float16)w0.w;
            bb[4] = (_Float16)w1.x; bb[5] = (_Float16)w1.y;
            bb[6] = (_Float16)w1.z; bb[7] = (_Float16)w1.w;
            B[ks][ct] = bb;
        }
        __builtin_amdgcn_sched_barrier(0);
    }

    float bias[4];
#pragma unroll
    for (int ct = 0; ct < 4; ++ct) bias[ct] = b_rel[ct * 16 + col];

    int nodebase = blockIdx.x * 128 + w * 32;

    f32x4 acc[2][4];
#pragma unroll
    for (int nt = 0; nt < 2; ++nt)
#pragma unroll
        for (int ct = 0; ct < 4; ++ct) acc[nt][ct] = (f32x4){0.f, 0.f, 0.f, 0.f};

#pragma unroll
    for (int ks = 0; ks < NK; ++ks) {
        const _Float16* base = (ks < NK / 2) ? agg : h;
        int koff = ((ks < NK / 2) ? ks : ks - NK / 2) * 32 + krow * 8;
#pragma unroll
        for (int nt = 0; nt < 2; ++nt) {
            int i = nodebase + nt * 16 + col;
            i = min(i, n - 1);
            f16x8 a = *(const f16x8*)(base + (size_t)i * WIN + koff);
#pragma unroll
            for (int ct = 0; ct < 4; ++ct)
                acc[nt][ct] = __builtin_amdgcn_mfma_f32_16x16x32_f16(
                    a, B[ks][ct], acc[nt][ct], 0, 0, 0);
        }
    }

#pragma unroll
    for (int nt = 0; nt < 2; ++nt) {
#pragma unroll
        for (int r = 0; r < 4; ++r) {
            int node = nodebase + nt * 16 + krow * 4 + r;
            if (node < n) {
#pragma unroll
                for (int ct = 0; ct < 4; ++ct) {
                    float v = acc[nt][ct][r] + bias[ct];
                    out[(size_t)node * 64 + ct * 16 + col] = (_Float16)fmaxf(v, 0.f);
                }
            }
        }
    }
}

// ------------------------------------------- pool (block per graph) + classifier
__global__ __launch_bounds__(256) void k_pool_cls(
    const _Float16* __restrict__ h3, const int* __restrict__ batch,
    const float* __restrict__ W_cls, const float* __restrict__ b_cls,
    float* __restrict__ out, int n)
{
    __shared__ float part[4][64];
    __shared__ float pool[64];
    __shared__ int range[2];
    int g = blockIdx.x;
    int t = threadIdx.x;

    if (t < 2) {
        int key = g + t;
        int lo = 0, hi = n;
        while (lo < hi) {
            int mid = (lo + hi) >> 1;
            if (batch[mid] < key) lo = mid + 1; else hi = mid;
        }
        range[t] = lo;
    }
    __syncthreads();
    int start = range[0], end = range[1];

    int j = t & 63;
    int sub = t >> 6;
    float local = 0.f;
    for (int i = start + sub; i < end; i += 4)
        local += (float)h3[(size_t)i * 64 + j];
    part[sub][j] = local;
    __syncthreads();

    if (t < 64) {
        float cnt = (float)(end - start);
        float inv = 1.0f / fmaxf(cnt, 1.0f);
        pool[t] = (part[0][t] + part[1][t] + part[2][t] + part[3][t]) * inv;
    }
    __syncthreads();

    if (t < 10) {
        float acc = b_cls[t];
#pragma unroll
        for (int k = 0; k < 64; ++k) acc += W_cls[t * 64 + k] * pool[k];
        out[(size_t)g * 10 + t] = acc;
    }
}

// ---------------------------------------------------------------- launch
extern "C" void kernel_launch(void* const* d_in, const int* in_sizes, int n_in,
                              void* d_out, int out_size, void* d_ws, size_t ws_size,
                              hipStream_t stream)
{
    const int* x        = (const int*)d_in[0];
    const int* ei       = (const int*)d_in[1];
    const int* batch    = (const int*)d_in[2];
    const float* shape_emb = (const float*)d_in[4];
    const float* color_emb = (const float*)d_in[5];
    const float* W_pre   = (const float*)d_in[6];
    const float* b_pre   = (const float*)d_in[7];
    const float* W_rel1  = (const float*)d_in[8];
    const float* b_rel1  = (const float*)d_in[9];
    const float* W_root1 = (const float*)d_in[10];
    const float* W_rel2  = (const float*)d_in[11];
    const float* b_rel2  = (const float*)d_in[12];
    const float* W_root2 = (const float*)d_in[13];
    const float* W_cls   = (const float*)d_in[14];
    const float* b_cls   = (const float*)d_in[15];

    const int n  = in_sizes[0] / 2;   // 100000
    const int nE = in_sizes[1] / 2;   // 1200000
    const int G  = NGRAPHS;
    const int* src = ei;
    const int* dst = ei + nE;

    // workspace (f16 elements):
    //  [0,n*32) h1B | [n*32,n*64) agg1B | [n*64,n*128) h2B | [n*128,n*192) agg2B
    //  h3B = [0,n*64)  (h1B+agg1B dead after conv1)
    //  tabB [128*32] after agg2B
    //  ints: code[n] | row_ptr[n+1] | hist8[8n] | total[n] | rank[E] | sorted[E]
    //        | bsum[64] | boffs[64]
    _Float16* us = (_Float16*)d_ws;
    _Float16* h1B   = us;
    _Float16* agg1B = us + (size_t)n * 32;
    _Float16* h2B   = us + (size_t)n * 64;
    _Float16* agg2B = us + (size_t)n * 128;
    _Float16* h3B   = us;
    _Float16* tabB  = us + (size_t)n * 192;
    int* ints    = (int*)(tabB + 128 * 32);
    int* code    = ints;                       // n
    int* row_ptr = code + n;                   // n+1
    int* hist8   = row_ptr + (n + 1);          // 8n
    int* total   = hist8 + (size_t)8 * n;      // n
    int* rank    = total + n;                  // E
    int* sorted  = rank + nE;                  // E
    int* bsum    = sorted + nE;                // <=64
    int* boffs   = bsum + 64;                  // <=64

    const int EB = (nE + 255) / 256;
    const int NB = (n + 255) / 256;
    const int CB = (n + 127) / 128;
    const int SB = (n + SCAN_CHUNK - 1) / SCAN_CHUNK;

    // --- CSR build + layer-1 table ---
    hipMemsetAsync(hist8, 0, (size_t)8 * n * sizeof(int), stream);
    k_pre<<<NB, 256, 0, stream>>>(x, shape_emb, color_emb, W_pre, b_pre, h1B, code, n);
    k_table<<<1, 128, 0, stream>>>(shape_emb, color_emb, W_pre, b_pre, tabB);
    k_hist8<<<EB, 256, 0, stream>>>(dst, hist8, rank, n, nE);
    k_combine<<<NB, 256, 0, stream>>>(hist8, total, n);
    k_scan_part<<<SB, 256, 0, stream>>>(total, bsum, n);
    k_scan_mid<<<1, 64, 0, stream>>>(bsum, boffs, row_ptr, SB, n);
    k_scan_apply<<<SB, 256, 0, stream>>>(total, boffs, row_ptr, n);
    k_scatteridx<<<EB, 256, 0, stream>>>(src, dst, row_ptr, hist8, rank, code, sorted, n, nE);

    // --- forward ---
    k_agg1_tab<<<((size_t)n * 4 + 255) / 256, 256, 0, stream>>>(row_ptr, sorted, tabB, agg1B, n);
    k_conv_mfma<32><<<CB, 256, 0, stream>>>(agg1B, h1B, W_rel1, b_rel1, W_root1, h2B, n);
    k_agg<64, 8><<<((size_t)n * 8 + 255) / 256, 256, 0, stream>>>(row_ptr, sorted, h2B, agg2B, n);
    k_conv_mfma<64><<<CB, 256, 0, stream>>>(agg2B, h2B, W_rel2, b_rel2, W_root2, h3B, n);
    k_pool_cls<<<G, 256, 0, stream>>>(h3B, batch, W_cls, b_cls, (float*)d_out, n);
}

// Round 10
// 288.231 us; speedup vs baseline: 1.0119x; 1.0119x over previous
//
#include <hip/hip_runtime.h>
#include <hip/hip_bf16.h>

// SPRGNN: 2-layer GraphConv GNN forward. CSR-gather, f16 activation storage,
// MFMA conv, f32 accumulate. N=100000, E=1200000, G=1000.
//
// R10: 16-bit-packed histogram counters (two nodes per 32-bit word) halve the
// atomic line footprint. R9's 8-way XCD privatization REVERTED: measured
// no-op -- device-scope atomics resolve at the memory-side point regardless
// of issuing XCD (per-XCD L2s can't own atomic lines), so privatization only
// added a combine pass + bigger memset. Layer-1 LDS table kept from R9.

#define NGRAPHS 1000
#define SCAN_CHUNK 4096
#define SRCMASK 0x1FFFF

typedef _Float16 f16x8 __attribute__((ext_vector_type(8)));
typedef float f32x4 __attribute__((ext_vector_type(4)));

// ---------------------------------------------------------------- CSR build
// pass 1: packed histogram; atomicAdd return -> this edge's rank within dst.
// hist16 word w holds counts for nodes 2w (lo16) and 2w+1 (hi16); in-degree
// << 65536 so halves never carry into each other.
__global__ __launch_bounds__(256) void k_hist(const int* __restrict__ dst,
                                              unsigned* __restrict__ hist16,
                                              int* __restrict__ rank, int nE)
{
    int e = blockIdx.x * 256 + threadIdx.x;
    if (e >= nE) return;
    int d = dst[e];
    int sh = (d & 1) * 16;
    unsigned old = atomicAdd(&hist16[d >> 1], 1u << sh);
    rank[e] = (old >> sh) & 0xffff;
}

__device__ __forceinline__ int hval(const unsigned* hist16, int i) {
    return (hist16[i >> 1] >> ((i & 1) * 16)) & 0xffff;
}

__global__ __launch_bounds__(256) void k_scan_part(const unsigned* __restrict__ hist16,
                                                   int* __restrict__ bsum, int n)
{
    __shared__ int s[256];
    int t = threadIdx.x;
    int beg = blockIdx.x * SCAN_CHUNK + t * 16;
    int sum = 0;
#pragma unroll
    for (int q = 0; q < 16; q += 2) {
        int i = beg + q;
        if (i < n) {
            unsigned w = hist16[i >> 1];
            sum += (w & 0xffff);
            if (i + 1 < n) sum += (w >> 16);
        }
    }
    s[t] = sum;
    __syncthreads();
    for (int off = 128; off > 0; off >>= 1) {
        if (t < off) s[t] += s[t + off];
        __syncthreads();
    }
    if (t == 0) bsum[blockIdx.x] = s[0];
}

__global__ __launch_bounds__(64) void k_scan_mid(const int* __restrict__ bsum,
                                                 int* __restrict__ boffs,
                                                 int* __restrict__ row_ptr,
                                                 int B, int n)
{
    if (threadIdx.x == 0) {
        int run = 0;
        for (int b = 0; b < B; ++b) {
            boffs[b] = run;
            run += bsum[b];
        }
        row_ptr[n] = run;
    }
}

__global__ __launch_bounds__(256) void k_scan_apply(const unsigned* __restrict__ hist16,
                                                    const int* __restrict__ boffs,
                                                    int* __restrict__ row_ptr, int n)
{
    __shared__ int s[256];
    int t = threadIdx.x;
    int beg = blockIdx.x * SCAN_CHUNK + t * 16;
    int v[16];
    int sum = 0;
#pragma unroll
    for (int q = 0; q < 16; q += 2) {
        int i = beg + q;
        unsigned w = (i < n) ? hist16[i >> 1] : 0u;
        v[q] = (i < n) ? (int)(w & 0xffff) : 0;
        v[q + 1] = (i + 1 < n) ? (int)(w >> 16) : 0;
        sum += v[q] + v[q + 1];
    }
    s[t] = sum;
    __syncthreads();
    for (int off = 1; off < 256; off <<= 1) {
        int x = (t >= off) ? s[t - off] : 0;
        __syncthreads();
        s[t] += x;
        __syncthreads();
    }
    int base = boffs[blockIdx.x] + ((t == 0) ? 0 : s[t - 1]);
#pragma unroll
    for (int q = 0; q < 16; ++q) {
        int i = beg + q;
        if (i < n) {
            row_ptr[i] = base;
            base += v[q];
        }
    }
}

// pass 2: atomic-free scatter; payload packs (code<<17)|src
__global__ __launch_bounds__(256) void k_scatteridx(
    const int* __restrict__ src, const int* __restrict__ dst,
    const int* __restrict__ row_ptr, const int* __restrict__ rank,
    const int* __restrict__ code, int* __restrict__ sorted, int nE)
{
    int e = blockIdx.x * 256 + threadIdx.x;
    if (e >= nE) return;
    int d = dst[e];
    int s = src[e];
    sorted[row_ptr[d] + rank[e]] = (code[s] << 17) | s;
}

// ---------------------------------------------------------------- K1: pre-MLP
// also emits code[i] = x0*8 + x1 (the h1-table index)
__global__ __launch_bounds__(256) void k_pre(
    const int* __restrict__ x,
    const float* __restrict__ shape_emb, const float* __restrict__ color_emb,
    const float* __restrict__ W_pre, const float* __restrict__ b_pre,
    _Float16* __restrict__ h1, int* __restrict__ code, int n)
{
    __shared__ float sW[32 * 16];
    __shared__ float sB[32];
    __shared__ float sSE[16 * 8];
    __shared__ float sCE[8 * 8];
    int t = threadIdx.x;
    for (int i = t; i < 32 * 16; i += 256) sW[i] = W_pre[i];
    if (t < 32) sB[t] = b_pre[t];
    for (int i = t; i < 16 * 8; i += 256) sSE[i] = shape_emb[i];
    if (t < 64) sCE[t] = color_emb[t];
    __syncthreads();

    int i = blockIdx.x * 256 + t;
    if (i >= n) return;
    int s = x[2 * i];
    int c = x[2 * i + 1];
    code[i] = (s << 3) | (c & 7);
    float in[16];
#pragma unroll
    for (int k = 0; k < 8; ++k) in[k] = sSE[s * 8 + k];
#pragma unroll
    for (int k = 0; k < 8; ++k) in[8 + k] = sCE[c * 8 + k];

    float acc[32];
#pragma unroll
    for (int j = 0; j < 32; ++j) acc[j] = sB[j];
#pragma unroll
    for (int k = 0; k < 16; ++k) {
        float v = in[k];
#pragma unroll
        for (int j = 0; j < 32; ++j) acc[j] += sW[j * 16 + k] * v;
    }
#pragma unroll
    for (int g = 0; g < 4; ++g) {
        f16x8 o;
#pragma unroll
        for (int q = 0; q < 8; ++q) o[q] = (_Float16)fmaxf(acc[g * 8 + q], 0.f);
        *(f16x8*)(h1 + (size_t)i * 32 + g * 8) = o;
    }
}

// ------------------------------------------ h1 table: one row per input combo
__global__ __launch_bounds__(128) void k_table(
    const float* __restrict__ shape_emb, const float* __restrict__ color_emb,
    const float* __restrict__ W_pre, const float* __restrict__ b_pre,
    _Float16* __restrict__ table)   // [128][32]
{
    int c = threadIdx.x;            // code
    int si = c >> 3, ci = c & 7;
    float in[16];
#pragma unroll
    for (int k = 0; k < 8; ++k) in[k] = shape_emb[si * 8 + k];
#pragma unroll
    for (int k = 0; k < 8; ++k) in[8 + k] = color_emb[ci * 8 + k];
    float acc[32];
#pragma unroll
    for (int j = 0; j < 32; ++j) acc[j] = b_pre[j];
#pragma unroll
    for (int k = 0; k < 16; ++k) {
        float v = in[k];
#pragma unroll
        for (int j = 0; j < 32; ++j) acc[j] += W_pre[j * 16 + k] * v;
    }
#pragma unroll
    for (int g = 0; g < 4; ++g) {
        f16x8 o;
#pragma unroll
        for (int q = 0; q < 8; ++q) o[q] = (_Float16)fmaxf(acc[g * 8 + q], 0.f);
        *(f16x8*)(table + (size_t)c * 32 + g * 8) = o;
    }
}

// --------------------------------- agg1: gather from LDS h1-table (no global)
__global__ __launch_bounds__(256) void k_agg1_tab(
    const int* __restrict__ row_ptr, const int* __restrict__ sorted,
    const _Float16* __restrict__ table, _Float16* __restrict__ agg, int n)
{
    __shared__ _Float16 tab[128 * 32];
    int t = threadIdx.x;
    for (int i = t * 8; i < 128 * 32; i += 256 * 8)
        *(f16x8*)(tab + i) = *(const f16x8*)(table + i);
    __syncthreads();

    int tid = blockIdx.x * 256 + t;
    int i = tid >> 2;
    int p = tid & 3;
    if (i >= n) return;
    float a[8] = {0, 0, 0, 0, 0, 0, 0, 0};
    float b[8] = {0, 0, 0, 0, 0, 0, 0, 0};
    int e0 = row_ptr[i], e1 = row_ptr[i + 1];
    const _Float16* tp = tab + p * 8;
    int e = e0;
    for (; e + 2 <= e1; e += 2) {
        int c0 = sorted[e] >> 17;
        int c1 = sorted[e + 1] >> 17;
        f16x8 r0 = *(const f16x8*)(tp + c0 * 32);
        f16x8 r1 = *(const f16x8*)(tp + c1 * 32);
#pragma unroll
        for (int q = 0; q < 8; ++q) { a[q] += (float)r0[q]; b[q] += (float)r1[q]; }
    }
    if (e < e1) {
        int c0 = sorted[e] >> 17;
        f16x8 r0 = *(const f16x8*)(tp + c0 * 32);
#pragma unroll
        for (int q = 0; q < 8; ++q) a[q] += (float)r0[q];
    }
    f16x8 o;
#pragma unroll
    for (int q = 0; q < 8; ++q) o[q] = (_Float16)(a[q] + b[q]);
    *(f16x8*)(agg + (size_t)i * 32 + p * 8) = o;
}

// ------------------------------------------------- agg2: gather via CSR (global)
template <int WIDTH, int PARTS>
__global__ __launch_bounds__(256) void k_agg(
    const int* __restrict__ row_ptr, const int* __restrict__ sorted,
    const _Float16* __restrict__ h, _Float16* __restrict__ agg, int n)
{
    int tid = blockIdx.x * 256 + threadIdx.x;
    int i = tid / PARTS;
    int p = tid % PARTS;
    if (i >= n) return;
    float a[8] = {0, 0, 0, 0, 0, 0, 0, 0};
    float b[8] = {0, 0, 0, 0, 0, 0, 0, 0};
    int e0 = row_ptr[i], e1 = row_ptr[i + 1];
    const _Float16* hp = h + p * 8;
    int e = e0;
    for (; e + 4 <= e1; e += 4) {
        int s0 = sorted[e] & SRCMASK;
        int s1 = sorted[e + 1] & SRCMASK;
        int s2 = sorted[e + 2] & SRCMASK;
        int s3 = sorted[e + 3] & SRCMASK;
        f16x8 r0 = *(const f16x8*)(hp + (size_t)s0 * WIDTH);
        f16x8 r1 = *(const f16x8*)(hp + (size_t)s1 * WIDTH);
        f16x8 r2 = *(const f16x8*)(hp + (size_t)s2 * WIDTH);
        f16x8 r3 = *(const f16x8*)(hp + (size_t)s3 * WIDTH);
#pragma unroll
        for (int q = 0; q < 8; ++q) {
            a[q] += (float)r0[q] + (float)r2[q];
            b[q] += (float)r1[q] + (float)r3[q];
        }
    }
    for (; e < e1; ++e) {
        int s0 = sorted[e] & SRCMASK;
        f16x8 r0 = *(const f16x8*)(hp + (size_t)s0 * WIDTH);
#pragma unroll
        for (int q = 0; q < 8; ++q) a[q] += (float)r0[q];
    }
    f16x8 o;
#pragma unroll
    for (int q = 0; q < 8; ++q) o[q] = (_Float16)(a[q] + b[q]);
    *(f16x8*)(agg + (size_t)i * WIDTH + p * 8) = o;
}

// ---------------------------------------------------- conv via MFMA
template <int WIN>
__global__ __launch_bounds__(256) void k_conv_mfma(
    const _Float16* __restrict__ agg, const _Float16* __restrict__ h,
    const float* __restrict__ W_rel, const float* __restrict__ b_rel,
    const float* __restrict__ W_root, _Float16* __restrict__ out, int n)
{
    constexpr int NK = (2 * WIN) / 32;
    int t = threadIdx.x;
    int lane = t & 63;
    int w = t >> 6;
    int col = lane & 15;
    int krow = lane >> 4;

    f16x8 B[NK][4];
#pragma unroll
    for (int ks = 0; ks < NK; ++ks) {
#pragma unroll
        for (int ct = 0; ct < 4; ++ct) {
            int j = ct * 16 + col;
            int kb = ks * 32 + krow * 8;
            const float* srcw = (ks < NK / 2)
                ? (W_rel + (size_t)j * WIN + kb)
                : (W_root + (size_t)j * WIN + (kb - WIN));
            float4 w0 = *(const float4*)(srcw);
            float4 w1 = *(const float4*)(srcw + 4);
            f16x8 bb;
            bb[0] = (_Float16)w0.x; bb[1] = (_Float16)w0.y;
            bb[2] = (_Float16)w0.z; bb[3] = (_Float16)w0.w;
            bb[4] = (_Float16)w1.x; bb[5] = (_Float16)w1.y;
            bb[6] = (_Float16)w1.z; bb[7] = (_Float16)w1.w;
            B[ks][ct] = bb;
        }
        __builtin_amdgcn_sched_barrier(0);
    }

    float bias[4];
#pragma unroll
    for (int ct = 0; ct < 4; ++ct) bias[ct] = b_rel[ct * 16 + col];

    int nodebase = blockIdx.x * 128 + w * 32;

    f32x4 acc[2][4];
#pragma unroll
    for (int nt = 0; nt < 2; ++nt)
#pragma unroll
        for (int ct = 0; ct < 4; ++ct) acc[nt][ct] = (f32x4){0.f, 0.f, 0.f, 0.f};

#pragma unroll
    for (int ks = 0; ks < NK; ++ks) {
        const _Float16* base = (ks < NK / 2) ? agg : h;
        int koff = ((ks < NK / 2) ? ks : ks - NK / 2) * 32 + krow * 8;
#pragma unroll
        for (int nt = 0; nt < 2; ++nt) {
            int i = nodebase + nt * 16 + col;
            i = min(i, n - 1);
            f16x8 a = *(const f16x8*)(base + (size_t)i * WIN + koff);
#pragma unroll
            for (int ct = 0; ct < 4; ++ct)
                acc[nt][ct] = __builtin_amdgcn_mfma_f32_16x16x32_f16(
                    a, B[ks][ct], acc[nt][ct], 0, 0, 0);
        }
    }

#pragma unroll
    for (int nt = 0; nt < 2; ++nt) {
#pragma unroll
        for (int r = 0; r < 4; ++r) {
            int node = nodebase + nt * 16 + krow * 4 + r;
            if (node < n) {
#pragma unroll
                for (int ct = 0; ct < 4; ++ct) {
                    float v = acc[nt][ct][r] + bias[ct];
                    out[(size_t)node * 64 + ct * 16 + col] = (_Float16)fmaxf(v, 0.f);
                }
            }
        }
    }
}

// ------------------------------------------- pool (block per graph) + classifier
__global__ __launch_bounds__(256) void k_pool_cls(
    const _Float16* __restrict__ h3, const int* __restrict__ batch,
    const float* __restrict__ W_cls, const float* __restrict__ b_cls,
    float* __restrict__ out, int n)
{
    __shared__ float part[4][64];
    __shared__ float pool[64];
    __shared__ int range[2];
    int g = blockIdx.x;
    int t = threadIdx.x;

    if (t < 2) {
        int key = g + t;
        int lo = 0, hi = n;
        while (lo < hi) {
            int mid = (lo + hi) >> 1;
            if (batch[mid] < key) lo = mid + 1; else hi = mid;
        }
        range[t] = lo;
    }
    __syncthreads();
    int start = range[0], end = range[1];

    int j = t & 63;
    int sub = t >> 6;
    float local = 0.f;
    for (int i = start + sub; i < end; i += 4)
        local += (float)h3[(size_t)i * 64 + j];
    part[sub][j] = local;
    __syncthreads();

    if (t < 64) {
        float cnt = (float)(end - start);
        float inv = 1.0f / fmaxf(cnt, 1.0f);
        pool[t] = (part[0][t] + part[1][t] + part[2][t] + part[3][t]) * inv;
    }
    __syncthreads();

    if (t < 10) {
        float acc = b_cls[t];
#pragma unroll
        for (int k = 0; k < 64; ++k) acc += W_cls[t * 64 + k] * pool[k];
        out[(size_t)g * 10 + t] = acc;
    }
}

// ---------------------------------------------------------------- launch
extern "C" void kernel_launch(void* const* d_in, const int* in_sizes, int n_in,
                              void* d_out, int out_size, void* d_ws, size_t ws_size,
                              hipStream_t stream)
{
    const int* x        = (const int*)d_in[0];
    const int* ei       = (const int*)d_in[1];
    const int* batch    = (const int*)d_in[2];
    const float* shape_emb = (const float*)d_in[4];
    const float* color_emb = (const float*)d_in[5];
    const float* W_pre   = (const float*)d_in[6];
    const float* b_pre   = (const float*)d_in[7];
    const float* W_rel1  = (const float*)d_in[8];
    const float* b_rel1  = (const float*)d_in[9];
    const float* W_root1 = (const float*)d_in[10];
    const float* W_rel2  = (const float*)d_in[11];
    const float* b_rel2  = (const float*)d_in[12];
    const float* W_root2 = (const float*)d_in[13];
    const float* W_cls   = (const float*)d_in[14];
    const float* b_cls   = (const float*)d_in[15];

    const int n  = in_sizes[0] / 2;   // 100000
    const int nE = in_sizes[1] / 2;   // 1200000
    const int G  = NGRAPHS;
    const int* src = ei;
    const int* dst = ei + nE;

    // workspace (f16 elements):
    //  [0,n*32) h1B | [n*32,n*64) agg1B | [n*64,n*128) h2B | [n*128,n*192) agg2B
    //  h3B = [0,n*64)  (h1B+agg1B dead after conv1)
    //  tabB [128*32] after agg2B
    //  ints: code[n] | row_ptr[n+1] | hist16[n/2+1 words] | rank[E] | sorted[E]
    //        | bsum[64] | boffs[64]
    _Float16* us = (_Float16*)d_ws;
    _Float16* h1B   = us;
    _Float16* agg1B = us + (size_t)n * 32;
    _Float16* h2B   = us + (size_t)n * 64;
    _Float16* agg2B = us + (size_t)n * 128;
    _Float16* h3B   = us;
    _Float16* tabB  = us + (size_t)n * 192;
    int* ints    = (int*)(tabB + 128 * 32);
    int* code    = ints;                       // n
    int* row_ptr = code + n;                   // n+1
    unsigned* hist16 = (unsigned*)(row_ptr + (n + 1));  // n/2+1 words
    int* rank    = (int*)(hist16 + (n / 2 + 1));        // E
    int* sorted  = rank + nE;                  // E
    int* bsum    = sorted + nE;                // <=64
    int* boffs   = bsum + 64;                  // <=64

    const int EB = (nE + 255) / 256;
    const int NB = (n + 255) / 256;
    const int CB = (n + 127) / 128;
    const int SB = (n + SCAN_CHUNK - 1) / SCAN_CHUNK;

    // --- CSR build + layer-1 table ---
    hipMemsetAsync(hist16, 0, (size_t)(n / 2 + 1) * sizeof(unsigned), stream);
    k_pre<<<NB, 256, 0, stream>>>(x, shape_emb, color_emb, W_pre, b_pre, h1B, code, n);
    k_table<<<1, 128, 0, stream>>>(shape_emb, color_emb, W_pre, b_pre, tabB);
    k_hist<<<EB, 256, 0, stream>>>(dst, hist16, rank, nE);
    k_scan_part<<<SB, 256, 0, stream>>>(hist16, bsum, n);
    k_scan_mid<<<1, 64, 0, stream>>>(bsum, boffs, row_ptr, SB, n);
    k_scan_apply<<<SB, 256, 0, stream>>>(hist16, boffs, row_ptr, n);
    k_scatteridx<<<EB, 256, 0, stream>>>(src, dst, row_ptr, rank, code, sorted, nE);

    // --- forward ---
    k_agg1_tab<<<((size_t)n * 4 + 255) / 256, 256, 0, stream>>>(row_ptr, sorted, tabB, agg1B, n);
    k_conv_mfma<32><<<CB, 256, 0, stream>>>(agg1B, h1B, W_rel1, b_rel1, W_root1, h2B, n);
    k_agg<64, 8><<<((size_t)n * 8 + 255) / 256, 256, 0, stream>>>(row_ptr, sorted, h2B, agg2B, n);
    k_conv_mfma<64><<<CB, 256, 0, stream>>>(agg2B, h2B, W_rel2, b_rel2, W_root2, h3B, n);
    k_pool_cls<<<G, 256, 0, stream>>>(h3B, batch, W_cls, b_cls, (float*)d_out, n);
}

// Round 12
// 279.655 us; speedup vs baseline: 1.0430x; 1.0307x over previous
//
#include <hip/hip_runtime.h>
#include <hip/hip_bf16.h>

// SPRGNN: 2-layer GraphConv GNN forward. CSR-gather, f16 activation storage,
// MFMA conv, f32 accumulate. N=100000, E=1200000, G=1000.
//
// R11 (resubmit; previous round hit GPUAcquisitionTimeout, never ran):
// front-end fusion. Layer-1 has only 128 distinct inputs -> k_fused1
// does agg1 (from 8KB LDS table, in-register f32) + root (table row) + MFMA
// in one kernel. k_pre / k_agg1_tab / h1B / agg1B deleted. scatteridx packs
// code inline from x. HW model note (R8/R9/R10): global atomics write
// through memory-side (~32B/op HBM regardless of counter footprint) ->
// hist cost is atomic-count-bound; left untouched this round.

#define NGRAPHS 1000
#define SCAN_CHUNK 4096
#define SRCMASK 0x1FFFF

typedef _Float16 f16x8 __attribute__((ext_vector_type(8)));
typedef float f32x4 __attribute__((ext_vector_type(4)));

// ---------------------------------------------------------------- CSR build
// pass 1: packed histogram (two nodes per word); atomicAdd return -> rank.
__global__ __launch_bounds__(256) void k_hist(const int* __restrict__ dst,
                                              unsigned* __restrict__ hist16,
                                              int* __restrict__ rank, int nE)
{
    int e = blockIdx.x * 256 + threadIdx.x;
    if (e >= nE) return;
    int d = dst[e];
    int sh = (d & 1) * 16;
    unsigned old = atomicAdd(&hist16[d >> 1], 1u << sh);
    rank[e] = (old >> sh) & 0xffff;
}

__global__ __launch_bounds__(256) void k_scan_part(const unsigned* __restrict__ hist16,
                                                   int* __restrict__ bsum, int n)
{
    __shared__ int s[256];
    int t = threadIdx.x;
    int beg = blockIdx.x * SCAN_CHUNK + t * 16;
    int sum = 0;
#pragma unroll
    for (int q = 0; q < 16; q += 2) {
        int i = beg + q;
        if (i < n) {
            unsigned w = hist16[i >> 1];
            sum += (w & 0xffff);
            if (i + 1 < n) sum += (w >> 16);
        }
    }
    s[t] = sum;
    __syncthreads();
    for (int off = 128; off > 0; off >>= 1) {
        if (t < off) s[t] += s[t + off];
        __syncthreads();
    }
    if (t == 0) bsum[blockIdx.x] = s[0];
}

__global__ __launch_bounds__(64) void k_scan_mid(const int* __restrict__ bsum,
                                                 int* __restrict__ boffs,
                                                 int* __restrict__ row_ptr,
                                                 int B, int n)
{
    if (threadIdx.x == 0) {
        int run = 0;
        for (int b = 0; b < B; ++b) {
            boffs[b] = run;
            run += bsum[b];
        }
        row_ptr[n] = run;
    }
}

__global__ __launch_bounds__(256) void k_scan_apply(const unsigned* __restrict__ hist16,
                                                    const int* __restrict__ boffs,
                                                    int* __restrict__ row_ptr, int n)
{
    __shared__ int s[256];
    int t = threadIdx.x;
    int beg = blockIdx.x * SCAN_CHUNK + t * 16;
    int v[16];
    int sum = 0;
#pragma unroll
    for (int q = 0; q < 16; q += 2) {
        int i = beg + q;
        unsigned w = (i < n) ? hist16[i >> 1] : 0u;
        v[q] = (i < n) ? (int)(w & 0xffff) : 0;
        v[q + 1] = (i + 1 < n) ? (int)(w >> 16) : 0;
        sum += v[q] + v[q + 1];
    }
    s[t] = sum;
    __syncthreads();
    for (int off = 1; off < 256; off <<= 1) {
        int x = (t >= off) ? s[t - off] : 0;
        __syncthreads();
        s[t] += x;
        __syncthreads();
    }
    int base = boffs[blockIdx.x] + ((t == 0) ? 0 : s[t - 1]);
#pragma unroll
    for (int q = 0; q < 16; ++q) {
        int i = beg + q;
        if (i < n) {
            row_ptr[i] = base;
            base += v[q];
        }
    }
}

// pass 2: atomic-free scatter; payload packs (code<<17)|src, code from x.
__global__ __launch_bounds__(256) void k_scatteridx(
    const int* __restrict__ src, const int* __restrict__ dst,
    const int* __restrict__ x, const int* __restrict__ row_ptr,
    const int* __restrict__ rank, int* __restrict__ sorted, int nE)
{
    int e = blockIdx.x * 256 + threadIdx.x;
    if (e >= nE) return;
    int d = dst[e];
    int s = src[e];
    int2 xv = *(const int2*)(x + 2 * s);
    int c = (xv.x << 3) | (xv.y & 7);
    sorted[row_ptr[d] + rank[e]] = (c << 17) | s;
}

// ------------------------------------------ h1 table: one row per input combo
__global__ __launch_bounds__(128) void k_table(
    const float* __restrict__ shape_emb, const float* __restrict__ color_emb,
    const float* __restrict__ W_pre, const float* __restrict__ b_pre,
    _Float16* __restrict__ table)   // [128][32]
{
    int c = threadIdx.x;            // code
    int si = c >> 3, ci = c & 7;
    float in[16];
#pragma unroll
    for (int k = 0; k < 8; ++k) in[k] = shape_emb[si * 8 + k];
#pragma unroll
    for (int k = 0; k < 8; ++k) in[8 + k] = color_emb[ci * 8 + k];
    float acc[32];
#pragma unroll
    for (int j = 0; j < 32; ++j) acc[j] = b_pre[j];
#pragma unroll
    for (int k = 0; k < 16; ++k) {
        float v = in[k];
#pragma unroll
        for (int j = 0; j < 32; ++j) acc[j] += W_pre[j * 16 + k] * v;
    }
#pragma unroll
    for (int g = 0; g < 4; ++g) {
        f16x8 o;
#pragma unroll
        for (int q = 0; q < 8; ++q) o[q] = (_Float16)fmaxf(acc[g * 8 + q], 0.f);
        *(f16x8*)(table + (size_t)c * 32 + g * 8) = o;
    }
}

// --------------------------- fused conv1: table-agg + table-root + MFMA
// out[i][:] = relu(b + Wrel @ agg1[i] + Wroot @ h1[i]),
//   agg1[i] = sum_e tab[code(sorted[e])], h1[i] = tab[code(x[i])].
// Block = 256 thr = 4 waves; wave = 32 nodes (2 tiles x 16) x 64 ch.
// A-frag: row=lane&15, k=(lane>>4)*8+e.  D: col=lane&15, row=(lane>>4)*4+reg.
__global__ __launch_bounds__(256) void k_fused1(
    const int* __restrict__ row_ptr, const int* __restrict__ sorted,
    const int* __restrict__ x, const _Float16* __restrict__ table,
    const float* __restrict__ W_rel, const float* __restrict__ b_rel,
    const float* __restrict__ W_root, _Float16* __restrict__ out, int n)
{
    __shared__ _Float16 tab[128 * 32];
    int t = threadIdx.x;
    for (int i = t * 8; i < 128 * 32; i += 2048)
        *(f16x8*)(tab + i) = *(const f16x8*)(table + i);

    int lane = t & 63;
    int w = t >> 6;
    int col = lane & 15;
    int krow = lane >> 4;

    // B frags: ks=0 -> W_rel, ks=1 -> W_root (each one 32-wide K step)
    f16x8 B[2][4];
#pragma unroll
    for (int ks = 0; ks < 2; ++ks) {
#pragma unroll
        for (int ct = 0; ct < 4; ++ct) {
            int j = ct * 16 + col;
            const float* srcw = (ks == 0 ? W_rel : W_root) + (size_t)j * 32 + krow * 8;
            float4 w0 = *(const float4*)(srcw);
            float4 w1 = *(const float4*)(srcw + 4);
            f16x8 bb;
            bb[0] = (_Float16)w0.x; bb[1] = (_Float16)w0.y;
            bb[2] = (_Float16)w0.z; bb[3] = (_Float16)w0.w;
            bb[4] = (_Float16)w1.x; bb[5] = (_Float16)w1.y;
            bb[6] = (_Float16)w1.z; bb[7] = (_Float16)w1.w;
            B[ks][ct] = bb;
        }
        __builtin_amdgcn_sched_barrier(0);
    }
    float bias[4];
#pragma unroll
    for (int ct = 0; ct < 4; ++ct) bias[ct] = b_rel[ct * 16 + col];

    __syncthreads();

    int nodebase = blockIdx.x * 128 + w * 32;
    f32x4 acc[2][4];
#pragma unroll
    for (int nt = 0; nt < 2; ++nt)
#pragma unroll
        for (int ct = 0; ct < 4; ++ct) acc[nt][ct] = (f32x4){0.f, 0.f, 0.f, 0.f};

#pragma unroll
    for (int nt = 0; nt < 2; ++nt) {
        int i = nodebase + nt * 16 + col;
        int iC = min(i, n - 1);
        int e0 = row_ptr[iC];
        int e1 = (i < n) ? row_ptr[iC + 1] : e0;

        // agg1 in f32 from LDS table rows
        float a[8] = {0, 0, 0, 0, 0, 0, 0, 0};
        int e = e0;
        for (; e + 2 <= e1; e += 2) {
            int c0 = sorted[e] >> 17;
            int c1 = sorted[e + 1] >> 17;
            f16x8 r0 = *(const f16x8*)(tab + c0 * 32 + krow * 8);
            f16x8 r1 = *(const f16x8*)(tab + c1 * 32 + krow * 8);
#pragma unroll
            for (int q = 0; q < 8; ++q) a[q] += (float)r0[q] + (float)r1[q];
        }
        if (e < e1) {
            int c0 = sorted[e] >> 17;
            f16x8 r0 = *(const f16x8*)(tab + c0 * 32 + krow * 8);
#pragma unroll
            for (int q = 0; q < 8; ++q) a[q] += (float)r0[q];
        }
        f16x8 Aagg;
#pragma unroll
        for (int q = 0; q < 8; ++q) Aagg[q] = (_Float16)a[q];

        // root term: h1 row straight from table
        int2 xv = *(const int2*)(x + 2 * (size_t)iC);
        int code = (xv.x << 3) | (xv.y & 7);
        f16x8 Aroot = *(const f16x8*)(tab + code * 32 + krow * 8);

#pragma unroll
        for (int ct = 0; ct < 4; ++ct)
            acc[nt][ct] = __builtin_amdgcn_mfma_f32_16x16x32_f16(
                Aagg, B[0][ct], acc[nt][ct], 0, 0, 0);
#pragma unroll
        for (int ct = 0; ct < 4; ++ct)
            acc[nt][ct] = __builtin_amdgcn_mfma_f32_16x16x32_f16(
                Aroot, B[1][ct], acc[nt][ct], 0, 0, 0);
    }

    // epilogue: bias + relu + f16 store
#pragma unroll
    for (int nt = 0; nt < 2; ++nt) {
#pragma unroll
        for (int r = 0; r < 4; ++r) {
            int node = nodebase + nt * 16 + krow * 4 + r;
            if (node < n) {
#pragma unroll
                for (int ct = 0; ct < 4; ++ct) {
                    float v = acc[nt][ct][r] + bias[ct];
                    out[(size_t)node * 64 + ct * 16 + col] = (_Float16)fmaxf(v, 0.f);
                }
            }
        }
    }
}

// ------------------------------------------------- agg2: gather via CSR (global)
template <int WIDTH, int PARTS>
__global__ __launch_bounds__(256) void k_agg(
    const int* __restrict__ row_ptr, const int* __restrict__ sorted,
    const _Float16* __restrict__ h, _Float16* __restrict__ agg, int n)
{
    int tid = blockIdx.x * 256 + threadIdx.x;
    int i = tid / PARTS;
    int p = tid % PARTS;
    if (i >= n) return;
    float a[8] = {0, 0, 0, 0, 0, 0, 0, 0};
    float b[8] = {0, 0, 0, 0, 0, 0, 0, 0};
    int e0 = row_ptr[i], e1 = row_ptr[i + 1];
    const _Float16* hp = h + p * 8;
    int e = e0;
    for (; e + 4 <= e1; e += 4) {
        int s0 = sorted[e] & SRCMASK;
        int s1 = sorted[e + 1] & SRCMASK;
        int s2 = sorted[e + 2] & SRCMASK;
        int s3 = sorted[e + 3] & SRCMASK;
        f16x8 r0 = *(const f16x8*)(hp + (size_t)s0 * WIDTH);
        f16x8 r1 = *(const f16x8*)(hp + (size_t)s1 * WIDTH);
        f16x8 r2 = *(const f16x8*)(hp + (size_t)s2 * WIDTH);
        f16x8 r3 = *(const f16x8*)(hp + (size_t)s3 * WIDTH);
#pragma unroll
        for (int q = 0; q < 8; ++q) {
            a[q] += (float)r0[q] + (float)r2[q];
            b[q] += (float)r1[q] + (float)r3[q];
        }
    }
    for (; e < e1; ++e) {
        int s0 = sorted[e] & SRCMASK;
        f16x8 r0 = *(const f16x8*)(hp + (size_t)s0 * WIDTH);
#pragma unroll
        for (int q = 0; q < 8; ++q) a[q] += (float)r0[q];
    }
    f16x8 o;
#pragma unroll
    for (int q = 0; q < 8; ++q) o[q] = (_Float16)(a[q] + b[q]);
    *(f16x8*)(agg + (size_t)i * WIDTH + p * 8) = o;
}

// ---------------------------------------------------- conv2 via MFMA
template <int WIN>
__global__ __launch_bounds__(256) void k_conv_mfma(
    const _Float16* __restrict__ agg, const _Float16* __restrict__ h,
    const float* __restrict__ W_rel, const float* __restrict__ b_rel,
    const float* __restrict__ W_root, _Float16* __restrict__ out, int n)
{
    constexpr int NK = (2 * WIN) / 32;
    int t = threadIdx.x;
    int lane = t & 63;
    int w = t >> 6;
    int col = lane & 15;
    int krow = lane >> 4;

    f16x8 B[NK][4];
#pragma unroll
    for (int ks = 0; ks < NK; ++ks) {
#pragma unroll
        for (int ct = 0; ct < 4; ++ct) {
            int j = ct * 16 + col;
            int kb = ks * 32 + krow * 8;
            const float* srcw = (ks < NK / 2)
                ? (W_rel + (size_t)j * WIN + kb)
                : (W_root + (size_t)j * WIN + (kb - WIN));
            float4 w0 = *(const float4*)(srcw);
            float4 w1 = *(const float4*)(srcw + 4);
            f16x8 bb;
            bb[0] = (_Float16)w0.x; bb[1] = (_Float16)w0.y;
            bb[2] = (_Float16)w0.z; bb[3] = (_Float16)w0.w;
            bb[4] = (_Float16)w1.x; bb[5] = (_Float16)w1.y;
            bb[6] = (_Float16)w1.z; bb[7] = (_Float16)w1.w;
            B[ks][ct] = bb;
        }
        __builtin_amdgcn_sched_barrier(0);
    }

    float bias[4];
#pragma unroll
    for (int ct = 0; ct < 4; ++ct) bias[ct] = b_rel[ct * 16 + col];

    int nodebase = blockIdx.x * 128 + w * 32;

    f32x4 acc[2][4];
#pragma unroll
    for (int nt = 0; nt < 2; ++nt)
#pragma unroll
        for (int ct = 0; ct < 4; ++ct) acc[nt][ct] = (f32x4){0.f, 0.f, 0.f, 0.f};

#pragma unroll
    for (int ks = 0; ks < NK; ++ks) {
        const _Float16* base = (ks < NK / 2) ? agg : h;
        int koff = ((ks < NK / 2) ? ks : ks - NK / 2) * 32 + krow * 8;
#pragma unroll
        for (int nt = 0; nt < 2; ++nt) {
            int i = nodebase + nt * 16 + col;
            i = min(i, n - 1);
            f16x8 a = *(const f16x8*)(base + (size_t)i * WIN + koff);
#pragma unroll
            for (int ct = 0; ct < 4; ++ct)
                acc[nt][ct] = __builtin_amdgcn_mfma_f32_16x16x32_f16(
                    a, B[ks][ct], acc[nt][ct], 0, 0, 0);
        }
    }

#pragma unroll
    for (int nt = 0; nt < 2; ++nt) {
#pragma unroll
        for (int r = 0; r < 4; ++r) {
            int node = nodebase + nt * 16 + krow * 4 + r;
            if (node < n) {
#pragma unroll
                for (int ct = 0; ct < 4; ++ct) {
                    float v = acc[nt][ct][r] + bias[ct];
                    out[(size_t)node * 64 + ct * 16 + col] = (_Float16)fmaxf(v, 0.f);
                }
            }
        }
    }
}

// ------------------------------------------- pool (block per graph) + classifier
__global__ __launch_bounds__(256) void k_pool_cls(
    const _Float16* __restrict__ h3, const int* __restrict__ batch,
    const float* __restrict__ W_cls, const float* __restrict__ b_cls,
    float* __restrict__ out, int n)
{
    __shared__ float part[4][64];
    __shared__ float pool[64];
    __shared__ int range[2];
    int g = blockIdx.x;
    int t = threadIdx.x;

    if (t < 2) {
        int key = g + t;
        int lo = 0, hi = n;
        while (lo < hi) {
            int mid = (lo + hi) >> 1;
            if (batch[mid] < key) lo = mid + 1; else hi = mid;
        }
        range[t] = lo;
    }
    __syncthreads();
    int start = range[0], end = range[1];

    int j = t & 63;
    int sub = t >> 6;
    float local = 0.f;
    for (int i = start + sub; i < end; i += 4)
        local += (float)h3[(size_t)i * 64 + j];
    part[sub][j] = local;
    __syncthreads();

    if (t < 64) {
        float cnt = (float)(end - start);
        float inv = 1.0f / fmaxf(cnt, 1.0f);
        pool[t] = (part[0][t] + part[1][t] + part[2][t] + part[3][t]) * inv;
    }
    __syncthreads();

    if (t < 10) {
        float acc = b_cls[t];
#pragma unroll
        for (int k = 0; k < 64; ++k) acc += W_cls[t * 64 + k] * pool[k];
        out[(size_t)g * 10 + t] = acc;
    }
}

// ---------------------------------------------------------------- launch
extern "C" void kernel_launch(void* const* d_in, const int* in_sizes, int n_in,
                              void* d_out, int out_size, void* d_ws, size_t ws_size,
                              hipStream_t stream)
{
    const int* x        = (const int*)d_in[0];
    const int* ei       = (const int*)d_in[1];
    const int* batch    = (const int*)d_in[2];
    const float* shape_emb = (const float*)d_in[4];
    const float* color_emb = (const float*)d_in[5];
    const float* W_pre   = (const float*)d_in[6];
    const float* b_pre   = (const float*)d_in[7];
    const float* W_rel1  = (const float*)d_in[8];
    const float* b_rel1  = (const float*)d_in[9];
    const float* W_root1 = (const float*)d_in[10];
    const float* W_rel2  = (const float*)d_in[11];
    const float* b_rel2  = (const float*)d_in[12];
    const float* W_root2 = (const float*)d_in[13];
    const float* W_cls   = (const float*)d_in[14];
    const float* b_cls   = (const float*)d_in[15];

    const int n  = in_sizes[0] / 2;   // 100000
    const int nE = in_sizes[1] / 2;   // 1200000
    const int G  = NGRAPHS;
    const int* src = ei;
    const int* dst = ei + nE;

    // workspace (f16 elements), all disjoint:
    //  h2B [n*64] | agg2B [n*64] | h3B [n*64] | tabB [128*32]
    //  ints: row_ptr[n+1] | hist16[n/2+1] | rank[E] | sorted[E] | bsum | boffs
    _Float16* us = (_Float16*)d_ws;
    _Float16* h2B   = us;
    _Float16* agg2B = us + (size_t)n * 64;
    _Float16* h3B   = us + (size_t)n * 128;
    _Float16* tabB  = us + (size_t)n * 192;
    int* ints    = (int*)(tabB + 128 * 32);
    int* row_ptr = ints;                                // n+1
    unsigned* hist16 = (unsigned*)(row_ptr + (n + 1));  // n/2+1
    int* rank    = (int*)(hist16 + (n / 2 + 1));        // E
    int* sorted  = rank + nE;                           // E
    int* bsum    = sorted + nE;                         // <=64
    int* boffs   = bsum + 64;                           // <=64

    const int EB = (nE + 255) / 256;
    const int CB = (n + 127) / 128;
    const int SB = (n + SCAN_CHUNK - 1) / SCAN_CHUNK;

    // --- CSR build + layer-1 table ---
    hipMemsetAsync(hist16, 0, (size_t)(n / 2 + 1) * sizeof(unsigned), stream);
    k_table<<<1, 128, 0, stream>>>(shape_emb, color_emb, W_pre, b_pre, tabB);
    k_hist<<<EB, 256, 0, stream>>>(dst, hist16, rank, nE);
    k_scan_part<<<SB, 256, 0, stream>>>(hist16, bsum, n);
    k_scan_mid<<<1, 64, 0, stream>>>(bsum, boffs, row_ptr, SB, n);
    k_scan_apply<<<SB, 256, 0, stream>>>(hist16, boffs, row_ptr, n);
    k_scatteridx<<<EB, 256, 0, stream>>>(src, dst, x, row_ptr, rank, sorted, nE);

    // --- forward ---
    k_fused1<<<CB, 256, 0, stream>>>(row_ptr, sorted, x, tabB,
                                     W_rel1, b_rel1, W_root1, h2B, n);
    k_agg<64, 8><<<((size_t)n * 8 + 255) / 256, 256, 0, stream>>>(row_ptr, sorted, h2B, agg2B, n);
    k_conv_mfma<64><<<CB, 256, 0, stream>>>(agg2B, h2B, W_rel2, b_rel2, W_root2, h3B, n);
    k_pool_cls<<<G, 256, 0, stream>>>(h3B, batch, W_cls, b_cls, (float*)d_out, n);
}

// Round 14
// 253.844 us; speedup vs baseline: 1.1490x; 1.1017x over previous
//
#include <hip/hip_runtime.h>
#include <hip/hip_bf16.h>

// SPRGNN: 2-layer GraphConv GNN forward. CSR-gather, f16 activation storage,
// MFMA conv, f32 accumulate. N=100000, E=1200000, G=1000.
//
// R13 (resubmit x2; prior two rounds hit GPUAcquisitionTimeout, never ran):
// CSR build rewritten as a bucketed counting sort with LDS-only atomics.
// R8-R12 established: 1.2M global atomics cost ~54us / 42MB HBM no matter the
// counter layout (memory-side write-through, ~22G atomics/s). New build:
//   A k_bcount: per-block LDS hist over 391 dst-buckets (dst>>8) -> cnt[blk][b]
//   B 3-phase scan of cnt in (bucket,block) order -> offs_flat (+row_ptr[n])
//   C k_bpart: LDS-cursor replay -> packed (dstlocal|code|src) into bucket order
//   D k_bfinal: block-per-bucket, LDS hist+scan over 256 locals -> row_ptr +
//     final dst-sorted payload array (contiguous region per bucket)
// k_hist / k_scatteridx / old scans / memset deleted. Forward path unchanged.

#define NGRAPHS 1000
#define SCAN_CHUNK 4096
#define EPB 4096          // edges per block in passes A/C
#define SRCMASK 0x1FFFF

typedef _Float16 f16x8 __attribute__((ext_vector_type(8)));
typedef float f32x4 __attribute__((ext_vector_type(4)));

// ---------------------------------------------- pass A: per-block bucket hist
__global__ __launch_bounds__(256) void k_bcount(const int* __restrict__ dst,
                                                int* __restrict__ cnt,
                                                int nE, int nbuck)
{
    __shared__ int h[512];
    int t = threadIdx.x;
    for (int i = t; i < nbuck; i += 256) h[i] = 0;
    __syncthreads();
    int base = blockIdx.x * EPB;
#pragma unroll
    for (int q = 0; q < 16; ++q) {
        int e = base + q * 256 + t;
        if (e < nE) atomicAdd(&h[dst[e] >> 8], 1);
    }
    __syncthreads();
    int* out = cnt + (size_t)blockIdx.x * nbuck;
    for (int i = t; i < nbuck; i += 256) out[i] = h[i];
}

// ------------------------- pass B: exclusive scan of cnt in (bucket,blk) order
// logical element i: b = i/nblka, k = i%nblka, val = cnt[k*nbuck+b].
__global__ __launch_bounds__(256) void k_pscan_part(const int* __restrict__ cnt,
                                                    int* __restrict__ bsum,
                                                    int L, int nbuck, int nblka)
{
    __shared__ int s[256];
    int t = threadIdx.x;
    int beg = blockIdx.x * SCAN_CHUNK + t * 16;
    int sum = 0;
#pragma unroll
    for (int q = 0; q < 16; ++q) {
        int i = beg + q;
        if (i < L) {
            int b = i / nblka, k = i - b * nblka;
            sum += cnt[(size_t)k * nbuck + b];
        }
    }
    s[t] = sum;
    __syncthreads();
    for (int off = 128; off > 0; off >>= 1) {
        if (t < off) s[t] += s[t + off];
        __syncthreads();
    }
    if (t == 0) bsum[blockIdx.x] = s[0];
}

// serial scan of <=64 block sums; also writes row_ptr[n] = total (= nE)
__global__ __launch_bounds__(64) void k_scan_mid(const int* __restrict__ bsum,
                                                 int* __restrict__ boffs,
                                                 int* __restrict__ row_ptr,
                                                 int B, int n)
{
    if (threadIdx.x == 0) {
        int run = 0;
        for (int b = 0; b < B; ++b) {
            boffs[b] = run;
            run += bsum[b];
        }
        row_ptr[n] = run;
    }
}

__global__ __launch_bounds__(256) void k_pscan_apply(const int* __restrict__ cnt,
                                                     const int* __restrict__ boffs,
                                                     int* __restrict__ offs_flat,
                                                     int L, int nbuck, int nblka)
{
    __shared__ int s[256];
    int t = threadIdx.x;
    int beg = blockIdx.x * SCAN_CHUNK + t * 16;
    int v[16];
    int sum = 0;
#pragma unroll
    for (int q = 0; q < 16; ++q) {
        int i = beg + q;
        if (i < L) {
            int b = i / nblka, k = i - b * nblka;
            v[q] = cnt[(size_t)k * nbuck + b];
        } else v[q] = 0;
        sum += v[q];
    }
    s[t] = sum;
    __syncthreads();
    for (int off = 1; off < 256; off <<= 1) {
        int x2 = (t >= off) ? s[t - off] : 0;
        __syncthreads();
        s[t] += x2;
        __syncthreads();
    }
    int base = boffs[blockIdx.x] + ((t == 0) ? 0 : s[t - 1]);
#pragma unroll
    for (int q = 0; q < 16; ++q) {
        int i = beg + q;
        if (i < L) {
            offs_flat[i] = base;
            base += v[q];
        }
    }
}

// ---------------------- pass C: partition edges into buckets (LDS cursors)
// payload: (dst&255)<<24 | code<<17 | src  (8+7+17 = 32 bits exactly)
__global__ __launch_bounds__(256) void k_bpart(
    const int* __restrict__ src, const int* __restrict__ dst,
    const int* __restrict__ x, const int* __restrict__ offs_flat,
    unsigned* __restrict__ part, int nE, int nblka)
{
    __shared__ int h[512];
    int t = threadIdx.x;
    for (int i = t; i < 512; i += 256) h[i] = 0;
    __syncthreads();
    int base = blockIdx.x * EPB;
#pragma unroll
    for (int q = 0; q < 16; ++q) {
        int e = base + q * 256 + t;
        if (e < nE) {
            int d = dst[e];
            int b = d >> 8;
            int r = atomicAdd(&h[b], 1);
            int s = src[e];
            int2 xv = *(const int2*)(x + 2 * (size_t)s);
            unsigned code = (unsigned)((xv.x << 3) | (xv.y & 7));
            unsigned payload = ((unsigned)(d & 255) << 24) | (code << 17) | (unsigned)s;
            part[offs_flat[(size_t)b * nblka + blockIdx.x] + r] = payload;
        }
    }
}

// ------------- pass D: per-bucket CSR finalize (block = bucket of <=256 nodes)
__global__ __launch_bounds__(256) void k_bfinal(
    const unsigned* __restrict__ part, const int* __restrict__ offs_flat,
    int* __restrict__ row_ptr, int* __restrict__ sorted,
    int n, int nbuck, int nblka, int nE)
{
    __shared__ int h[256];
    __shared__ int cur[256];
    int b = blockIdx.x;
    int t = threadIdx.x;
    int ebeg = offs_flat[(size_t)b * nblka];
    int eend = (b + 1 < nbuck) ? offs_flat[(size_t)(b + 1) * nblka] : nE;

    h[t] = 0;
    __syncthreads();
    for (int e = ebeg + t; e < eend; e += 256)
        atomicAdd(&h[part[e] >> 24], 1);
    __syncthreads();
    int myv = h[t];
    // in-place Hillis-Steele inclusive scan
    for (int off = 1; off < 256; off <<= 1) {
        int x2 = (t >= off) ? h[t - off] : 0;
        __syncthreads();
        h[t] += x2;
        __syncthreads();
    }
    int excl = h[t] - myv;
    int node = b * 256 + t;
    if (node < n) row_ptr[node] = ebeg + excl;
    cur[t] = ebeg + excl;
    __syncthreads();
    for (int e = ebeg + t; e < eend; e += 256) {
        unsigned u = part[e];
        int r = atomicAdd(&cur[u >> 24], 1);
        sorted[r] = (int)(u & 0xFFFFFFu);
    }
}

// ------------------------------------------ h1 table: one row per input combo
__global__ __launch_bounds__(128) void k_table(
    const float* __restrict__ shape_emb, const float* __restrict__ color_emb,
    const float* __restrict__ W_pre, const float* __restrict__ b_pre,
    _Float16* __restrict__ table)   // [128][32]
{
    int c = threadIdx.x;            // code
    int si = c >> 3, ci = c & 7;
    float in[16];
#pragma unroll
    for (int k = 0; k < 8; ++k) in[k] = shape_emb[si * 8 + k];
#pragma unroll
    for (int k = 0; k < 8; ++k) in[8 + k] = color_emb[ci * 8 + k];
    float acc[32];
#pragma unroll
    for (int j = 0; j < 32; ++j) acc[j] = b_pre[j];
#pragma unroll
    for (int k = 0; k < 16; ++k) {
        float v = in[k];
#pragma unroll
        for (int j = 0; j < 32; ++j) acc[j] += W_pre[j * 16 + k] * v;
    }
#pragma unroll
    for (int g = 0; g < 4; ++g) {
        f16x8 o;
#pragma unroll
        for (int q = 0; q < 8; ++q) o[q] = (_Float16)fmaxf(acc[g * 8 + q], 0.f);
        *(f16x8*)(table + (size_t)c * 32 + g * 8) = o;
    }
}

// --------------------------- fused conv1: table-agg + table-root + MFMA
__global__ __launch_bounds__(256) void k_fused1(
    const int* __restrict__ row_ptr, const int* __restrict__ sorted,
    const int* __restrict__ x, const _Float16* __restrict__ table,
    const float* __restrict__ W_rel, const float* __restrict__ b_rel,
    const float* __restrict__ W_root, _Float16* __restrict__ out, int n)
{
    __shared__ _Float16 tab[128 * 32];
    int t = threadIdx.x;
    for (int i = t * 8; i < 128 * 32; i += 2048)
        *(f16x8*)(tab + i) = *(const f16x8*)(table + i);

    int lane = t & 63;
    int w = t >> 6;
    int col = lane & 15;
    int krow = lane >> 4;

    f16x8 B[2][4];
#pragma unroll
    for (int ks = 0; ks < 2; ++ks) {
#pragma unroll
        for (int ct = 0; ct < 4; ++ct) {
            int j = ct * 16 + col;
            const float* srcw = (ks == 0 ? W_rel : W_root) + (size_t)j * 32 + krow * 8;
            float4 w0 = *(const float4*)(srcw);
            float4 w1 = *(const float4*)(srcw + 4);
            f16x8 bb;
            bb[0] = (_Float16)w0.x; bb[1] = (_Float16)w0.y;
            bb[2] = (_Float16)w0.z; bb[3] = (_Float16)w0.w;
            bb[4] = (_Float16)w1.x; bb[5] = (_Float16)w1.y;
            bb[6] = (_Float16)w1.z; bb[7] = (_Float16)w1.w;
            B[ks][ct] = bb;
        }
        __builtin_amdgcn_sched_barrier(0);
    }
    float bias[4];
#pragma unroll
    for (int ct = 0; ct < 4; ++ct) bias[ct] = b_rel[ct * 16 + col];

    __syncthreads();

    int nodebase = blockIdx.x * 128 + w * 32;
    f32x4 acc[2][4];
#pragma unroll
    for (int nt = 0; nt < 2; ++nt)
#pragma unroll
        for (int ct = 0; ct < 4; ++ct) acc[nt][ct] = (f32x4){0.f, 0.f, 0.f, 0.f};

#pragma unroll
    for (int nt = 0; nt < 2; ++nt) {
        int i = nodebase + nt * 16 + col;
        int iC = min(i, n - 1);
        int e0 = row_ptr[iC];
        int e1 = (i < n) ? row_ptr[iC + 1] : e0;

        float a[8] = {0, 0, 0, 0, 0, 0, 0, 0};
        int e = e0;
        for (; e + 2 <= e1; e += 2) {
            int c0 = sorted[e] >> 17;
            int c1 = sorted[e + 1] >> 17;
            f16x8 r0 = *(const f16x8*)(tab + c0 * 32 + krow * 8);
            f16x8 r1 = *(const f16x8*)(tab + c1 * 32 + krow * 8);
#pragma unroll
            for (int q = 0; q < 8; ++q) a[q] += (float)r0[q] + (float)r1[q];
        }
        if (e < e1) {
            int c0 = sorted[e] >> 17;
            f16x8 r0 = *(const f16x8*)(tab + c0 * 32 + krow * 8);
#pragma unroll
            for (int q = 0; q < 8; ++q) a[q] += (float)r0[q];
        }
        f16x8 Aagg;
#pragma unroll
        for (int q = 0; q < 8; ++q) Aagg[q] = (_Float16)a[q];

        int2 xv = *(const int2*)(x + 2 * (size_t)iC);
        int code = (xv.x << 3) | (xv.y & 7);
        f16x8 Aroot = *(const f16x8*)(tab + code * 32 + krow * 8);

#pragma unroll
        for (int ct = 0; ct < 4; ++ct)
            acc[nt][ct] = __builtin_amdgcn_mfma_f32_16x16x32_f16(
                Aagg, B[0][ct], acc[nt][ct], 0, 0, 0);
#pragma unroll
        for (int ct = 0; ct < 4; ++ct)
            acc[nt][ct] = __builtin_amdgcn_mfma_f32_16x16x32_f16(
                Aroot, B[1][ct], acc[nt][ct], 0, 0, 0);
    }

#pragma unroll
    for (int nt = 0; nt < 2; ++nt) {
#pragma unroll
        for (int r = 0; r < 4; ++r) {
            int node = nodebase + nt * 16 + krow * 4 + r;
            if (node < n) {
#pragma unroll
                for (int ct = 0; ct < 4; ++ct) {
                    float v = acc[nt][ct][r] + bias[ct];
                    out[(size_t)node * 64 + ct * 16 + col] = (_Float16)fmaxf(v, 0.f);
                }
            }
        }
    }
}

// ------------------------------------------------- agg2: gather via CSR (global)
template <int WIDTH, int PARTS>
__global__ __launch_bounds__(256) void k_agg(
    const int* __restrict__ row_ptr, const int* __restrict__ sorted,
    const _Float16* __restrict__ h, _Float16* __restrict__ agg, int n)
{
    int tid = blockIdx.x * 256 + threadIdx.x;
    int i = tid / PARTS;
    int p = tid % PARTS;
    if (i >= n) return;
    float a[8] = {0, 0, 0, 0, 0, 0, 0, 0};
    float b[8] = {0, 0, 0, 0, 0, 0, 0, 0};
    int e0 = row_ptr[i], e1 = row_ptr[i + 1];
    const _Float16* hp = h + p * 8;
    int e = e0;
    for (; e + 4 <= e1; e += 4) {
        int s0 = sorted[e] & SRCMASK;
        int s1 = sorted[e + 1] & SRCMASK;
        int s2 = sorted[e + 2] & SRCMASK;
        int s3 = sorted[e + 3] & SRCMASK;
        f16x8 r0 = *(const f16x8*)(hp + (size_t)s0 * WIDTH);
        f16x8 r1 = *(const f16x8*)(hp + (size_t)s1 * WIDTH);
        f16x8 r2 = *(const f16x8*)(hp + (size_t)s2 * WIDTH);
        f16x8 r3 = *(const f16x8*)(hp + (size_t)s3 * WIDTH);
#pragma unroll
        for (int q = 0; q < 8; ++q) {
            a[q] += (float)r0[q] + (float)r2[q];
            b[q] += (float)r1[q] + (float)r3[q];
        }
    }
    for (; e < e1; ++e) {
        int s0 = sorted[e] & SRCMASK;
        f16x8 r0 = *(const f16x8*)(hp + (size_t)s0 * WIDTH);
#pragma unroll
        for (int q = 0; q < 8; ++q) a[q] += (float)r0[q];
    }
    f16x8 o;
#pragma unroll
    for (int q = 0; q < 8; ++q) o[q] = (_Float16)(a[q] + b[q]);
    *(f16x8*)(agg + (size_t)i * WIDTH + p * 8) = o;
}

// ---------------------------------------------------- conv2 via MFMA
template <int WIN>
__global__ __launch_bounds__(256) void k_conv_mfma(
    const _Float16* __restrict__ agg, const _Float16* __restrict__ h,
    const float* __restrict__ W_rel, const float* __restrict__ b_rel,
    const float* __restrict__ W_root, _Float16* __restrict__ out, int n)
{
    constexpr int NK = (2 * WIN) / 32;
    int t = threadIdx.x;
    int lane = t & 63;
    int w = t >> 6;
    int col = lane & 15;
    int krow = lane >> 4;

    f16x8 B[NK][4];
#pragma unroll
    for (int ks = 0; ks < NK; ++ks) {
#pragma unroll
        for (int ct = 0; ct < 4; ++ct) {
            int j = ct * 16 + col;
            int kb = ks * 32 + krow * 8;
            const float* srcw = (ks < NK / 2)
                ? (W_rel + (size_t)j * WIN + kb)
                : (W_root + (size_t)j * WIN + (kb - WIN));
            float4 w0 = *(const float4*)(srcw);
            float4 w1 = *(const float4*)(srcw + 4);
            f16x8 bb;
            bb[0] = (_Float16)w0.x; bb[1] = (_Float16)w0.y;
            bb[2] = (_Float16)w0.z; bb[3] = (_Float16)w0.w;
            bb[4] = (_Float16)w1.x; bb[5] = (_Float16)w1.y;
            bb[6] = (_Float16)w1.z; bb[7] = (_Float16)w1.w;
            B[ks][ct] = bb;
        }
        __builtin_amdgcn_sched_barrier(0);
    }

    float bias[4];
#pragma unroll
    for (int ct = 0; ct < 4; ++ct) bias[ct] = b_rel[ct * 16 + col];

    int nodebase = blockIdx.x * 128 + w * 32;

    f32x4 acc[2][4];
#pragma unroll
    for (int nt = 0; nt < 2; ++nt)
#pragma unroll
        for (int ct = 0; ct < 4; ++ct) acc[nt][ct] = (f32x4){0.f, 0.f, 0.f, 0.f};

#pragma unroll
    for (int ks = 0; ks < NK; ++ks) {
        const _Float16* base = (ks < NK / 2) ? agg : h;
        int koff = ((ks < NK / 2) ? ks : ks - NK / 2) * 32 + krow * 8;
#pragma unroll
        for (int nt = 0; nt < 2; ++nt) {
            int i = nodebase + nt * 16 + col;
            i = min(i, n - 1);
            f16x8 a = *(const f16x8*)(base + (size_t)i * WIN + koff);
#pragma unroll
            for (int ct = 0; ct < 4; ++ct)
                acc[nt][ct] = __builtin_amdgcn_mfma_f32_16x16x32_f16(
                    a, B[ks][ct], acc[nt][ct], 0, 0, 0);
        }
    }

#pragma unroll
    for (int nt = 0; nt < 2; ++nt) {
#pragma unroll
        for (int r = 0; r < 4; ++r) {
            int node = nodebase + nt * 16 + krow * 4 + r;
            if (node < n) {
#pragma unroll
                for (int ct = 0; ct < 4; ++ct) {
                    float v = acc[nt][ct][r] + bias[ct];
                    out[(size_t)node * 64 + ct * 16 + col] = (_Float16)fmaxf(v, 0.f);
                }
            }
        }
    }
}

// ------------------------------------------- pool (block per graph) + classifier
__global__ __launch_bounds__(256) void k_pool_cls(
    const _Float16* __restrict__ h3, const int* __restrict__ batch,
    const float* __restrict__ W_cls, const float* __restrict__ b_cls,
    float* __restrict__ out, int n)
{
    __shared__ float part[4][64];
    __shared__ float pool[64];
    __shared__ int range[2];
    int g = blockIdx.x;
    int t = threadIdx.x;

    if (t < 2) {
        int key = g + t;
        int lo = 0, hi = n;
        while (lo < hi) {
            int mid = (lo + hi) >> 1;
            if (batch[mid] < key) lo = mid + 1; else hi = mid;
        }
        range[t] = lo;
    }
    __syncthreads();
    int start = range[0], end = range[1];

    int j = t & 63;
    int sub = t >> 6;
    float local = 0.f;
    for (int i = start + sub; i < end; i += 4)
        local += (float)h3[(size_t)i * 64 + j];
    part[sub][j] = local;
    __syncthreads();

    if (t < 64) {
        float cnt = (float)(end - start);
        float inv = 1.0f / fmaxf(cnt, 1.0f);
        pool[t] = (part[0][t] + part[1][t] + part[2][t] + part[3][t]) * inv;
    }
    __syncthreads();

    if (t < 10) {
        float acc = b_cls[t];
#pragma unroll
        for (int k = 0; k < 64; ++k) acc += W_cls[t * 64 + k] * pool[k];
        out[(size_t)g * 10 + t] = acc;
    }
}

// ---------------------------------------------------------------- launch
extern "C" void kernel_launch(void* const* d_in, const int* in_sizes, int n_in,
                              void* d_out, int out_size, void* d_ws, size_t ws_size,
                              hipStream_t stream)
{
    const int* x        = (const int*)d_in[0];
    const int* ei       = (const int*)d_in[1];
    const int* batch    = (const int*)d_in[2];
    const float* shape_emb = (const float*)d_in[4];
    const float* color_emb = (const float*)d_in[5];
    const float* W_pre   = (const float*)d_in[6];
    const float* b_pre   = (const float*)d_in[7];
    const float* W_rel1  = (const float*)d_in[8];
    const float* b_rel1  = (const float*)d_in[9];
    const float* W_root1 = (const float*)d_in[10];
    const float* W_rel2  = (const float*)d_in[11];
    const float* b_rel2  = (const float*)d_in[12];
    const float* W_root2 = (const float*)d_in[13];
    const float* W_cls   = (const float*)d_in[14];
    const float* b_cls   = (const float*)d_in[15];

    const int n  = in_sizes[0] / 2;   // 100000
    const int nE = in_sizes[1] / 2;   // 1200000
    const int G  = NGRAPHS;
    const int* src = ei;
    const int* dst = ei + nE;

    const int NBUCK = (n + 255) >> 8;              // 391
    const int NBLKA = (nE + EPB - 1) / EPB;        // 293
    const int L     = NBUCK * NBLKA;               // ~114563
    const int SBL   = (L + SCAN_CHUNK - 1) / SCAN_CHUNK;  // 28

    // workspace (f16 elements), all disjoint:
    //  h2B [n*64] | agg2B [n*64] | h3B [n*64] | tabB [128*32]
    //  ints: row_ptr[n+1] | cnt[L] | offs_flat[L] | part[E] | sorted[E]
    //        | bsum[64] | boffs[64]
    _Float16* us = (_Float16*)d_ws;
    _Float16* h2B   = us;
    _Float16* agg2B = us + (size_t)n * 64;
    _Float16* h3B   = us + (size_t)n * 128;
    _Float16* tabB  = us + (size_t)n * 192;
    int* ints      = (int*)(tabB + 128 * 32);
    int* row_ptr   = ints;                       // n+1
    int* cnt       = row_ptr + (n + 1);          // L
    int* offs_flat = cnt + L;                    // L
    unsigned* part = (unsigned*)(offs_flat + L); // E
    int* sorted    = (int*)(part + nE);          // E
    int* bsum      = sorted + nE;                // <=64
    int* boffs     = bsum + 64;                  // <=64

    const int CB = (n + 127) / 128;

    // --- CSR build (LDS-atomic counting sort) + layer-1 table ---
    k_table<<<1, 128, 0, stream>>>(shape_emb, color_emb, W_pre, b_pre, tabB);
    k_bcount<<<NBLKA, 256, 0, stream>>>(dst, cnt, nE, NBUCK);
    k_pscan_part<<<SBL, 256, 0, stream>>>(cnt, bsum, L, NBUCK, NBLKA);
    k_scan_mid<<<1, 64, 0, stream>>>(bsum, boffs, row_ptr, SBL, n);
    k_pscan_apply<<<SBL, 256, 0, stream>>>(cnt, boffs, offs_flat, L, NBUCK, NBLKA);
    k_bpart<<<NBLKA, 256, 0, stream>>>(src, dst, x, offs_flat, part, nE, NBLKA);
    k_bfinal<<<NBUCK, 256, 0, stream>>>(part, offs_flat, row_ptr, sorted,
                                        n, NBUCK, NBLKA, nE);

    // --- forward ---
    k_fused1<<<CB, 256, 0, stream>>>(row_ptr, sorted, x, tabB,
                                     W_rel1, b_rel1, W_root1, h2B, n);
    k_agg<64, 8><<<((size_t)n * 8 + 255) / 256, 256, 0, stream>>>(row_ptr, sorted, h2B, agg2B, n);
    k_conv_mfma<64><<<CB, 256, 0, stream>>>(agg2B, h2B, W_rel2, b_rel2, W_root2, h3B, n);
    k_pool_cls<<<G, 256, 0, stream>>>(h3B, batch, W_cls, b_cls, (float*)d_out, n);
}